// Round 15
// baseline (123.309 us; speedup 1.0000x reference)
//
#include <hip/hip_runtime.h>
#include <hip/hip_bf16.h>

#define TT 2048
#define QSC 0.18033688011112042f   // 0.125 * log2(e)

typedef __attribute__((ext_vector_type(4))) float f32x4;
typedef __attribute__((ext_vector_type(8))) __bf16 bf16x8;
typedef __attribute__((ext_vector_type(4))) short short4v;
typedef __attribute__((ext_vector_type(8))) short short8v;

enum { M_CONV = 0, M_QKV = 1, M_PROJ = 2, M_FFN1 = 3, M_FFN2 = 4 };

__device__ __forceinline__ void gload16(const void* g, void* l) {
    __builtin_amdgcn_global_load_lds(
        (__attribute__((address_space(1))) void*)g,
        (__attribute__((address_space(3))) void*)l, 16, 0, 0);
}

__device__ __forceinline__ short f2bf(float f) {
    unsigned u = __float_as_uint(f);
    u = (u + 0x7fffu + ((u >> 16) & 1u)) >> 16;
    return (short)u;
}

__device__ __forceinline__ float bf2f(short s) {
    unsigned u = ((unsigned)(unsigned short)s) << 16;
    return __uint_as_float(u);
}

// ---------------------------------------------------------------------------
// One prep kernel, fully coalesced (round-13 proven).
// ---------------------------------------------------------------------------
__global__ __launch_bounds__(256) void prep_all(
    const float* __restrict__ conv_w, const float* __restrict__ x,
    const float* __restrict__ qkv_w, const float* __restrict__ proj_w,
    const float* __restrict__ f1w, const float* __restrict__ f2w,
    short* __restrict__ cwT, short* __restrict__ xpad,
    short* __restrict__ qkvT, short* __restrict__ projT,
    short* __restrict__ f1T, short* __restrict__ f2T) {
    if (blockIdx.x < 2048) {
        int t = blockIdx.x;
        const float* src; short* dst; int K, N, lt;
        if (t < 768)       { src = qkv_w;  dst = qkvT;  K = 512;  N = 1536; lt = t; }
        else if (t < 1024) { src = proj_w; dst = projT; K = 512;  N = 512;  lt = t - 768; }
        else if (t < 1536) { src = f1w;    dst = f1T;   K = 512;  N = 1024; lt = t - 1024; }
        else               { src = f2w;    dst = f2T;   K = 1024; N = 512;  lt = t - 1536; }
        int ntn = N >> 5;
        int kt = lt / ntn, nt = lt - kt * ntn;
        int k0 = kt * 32, n0 = nt * 32;
        __shared__ float tile[32][33];
        int c = threadIdx.x & 31, r = threadIdx.x >> 5;
        #pragma unroll
        for (int i = 0; i < 4; i++)
            tile[r + i * 8][c] = src[(size_t)(k0 + r + i * 8) * N + n0 + c];
        __syncthreads();
        #pragma unroll
        for (int i = 0; i < 4; i++)
            dst[(size_t)(n0 + r + i * 8) * K + k0 + c] = f2bf(tile[c][r + i * 8]);
        return;
    }
    if (blockIdx.x < 3072) {                  // conv_w OIH -> [o][tap*512+i]
        int oi = (blockIdx.x - 2048) * 256 + threadIdx.x;   // < 262144
        int o = oi >> 9, i = oi & 511;
        const float* s = conv_w + (size_t)oi * 3;
        #pragma unroll
        for (int tap = 0; tap < 3; tap++)
            cwT[(size_t)o * 1536 + tap * 512 + i] = f2bf(s[tap]);
        return;
    }
    int idx = (blockIdx.x - 3072) * 256 + threadIdx.x;      // < 262400
    int rp = idx >> 6, j = idx & 63;
    if (rp < 4100) {                          // x -> xpad [2][2050][512] bf16
        int bb = rp / 2050, rr = rp - bb * 2050;
        int t = rr - 2;
        short8v pk;
        if (t >= 0) {
            const float* xs = x + ((size_t)(bb << 11) + t) * 512 + j * 8;
            f32x4 a = *(const f32x4*)xs;
            f32x4 b2 = *(const f32x4*)(xs + 4);
            #pragma unroll
            for (int i = 0; i < 4; i++) { pk[i] = f2bf(a[i]); pk[i + 4] = f2bf(b2[i]); }
        } else {
            #pragma unroll
            for (int i = 0; i < 8; i++) pk[i] = 0;
        }
        *(short8v*)&xpad[(size_t)rp * 512 + j * 8] = pk;
    }
}

// ---------------------------------------------------------------------------
// Row LayerNorm, wave-per-row, bf16 input. 512 threads = 8 rows/block.
// ---------------------------------------------------------------------------
__global__ __launch_bounds__(512) void ln_row(const short* __restrict__ in,
                                              const float* __restrict__ g,
                                              const float* __restrict__ b,
                                              float* __restrict__ outf,
                                              short* __restrict__ outb) {
    int row = blockIdx.x * 8 + (threadIdx.x >> 6);
    int l = threadIdx.x & 63;
    short8v v = *(const short8v*)(in + (size_t)row * 512 + l * 8);
    float vf[8];
    float s = 0.f, ss = 0.f;
    #pragma unroll
    for (int i = 0; i < 8; i++) {
        vf[i] = bf2f(v[i]);
        s += vf[i]; ss += vf[i] * vf[i];
    }
    #pragma unroll
    for (int off = 1; off < 64; off <<= 1) {
        s  += __shfl_xor(s, off);
        ss += __shfl_xor(ss, off);
    }
    float mean = s * (1.f / 512);
    float var  = ss * (1.f / 512) - mean * mean;
    float rstd = rsqrtf(var + 1e-5f);
    f32x4 g0 = *(const f32x4*)(g + l * 8), g1 = *(const f32x4*)(g + l * 8 + 4);
    f32x4 b0 = *(const f32x4*)(b + l * 8), b1 = *(const f32x4*)(b + l * 8 + 4);
    float ov[8];
    #pragma unroll
    for (int i = 0; i < 4; i++) {
        ov[i]     = (vf[i]     - mean) * rstd * g0[i] + b0[i];
        ov[i + 4] = (vf[i + 4] - mean) * rstd * g1[i] + b1[i];
    }
    if (outf) {
        float* q = outf + (size_t)row * 512 + l * 8;
        *(f32x4*)q       = (f32x4){ov[0], ov[1], ov[2], ov[3]};
        *(f32x4*)(q + 4) = (f32x4){ov[4], ov[5], ov[6], ov[7]};
    }
    if (outb) {
        short8v pk;
        #pragma unroll
        for (int i = 0; i < 8; i++) pk[i] = f2bf(ov[i]);
        *(short8v*)(outb + (size_t)row * 512 + l * 8) = pk;
    }
}

// ---------------------------------------------------------------------------
// A-operand global address (handles conv's padded/3-tap layout)
// ---------------------------------------------------------------------------
template<int MODE>
__device__ __forceinline__ const short* a_ptr(const short* A, int m0, int r, int kk, int K) {
    if constexpr (MODE == M_CONV) {
        int row = m0 + r;
        int bb = row >> 11, t5 = row & 2047;
        int tap = kk >> 9, k2 = kk & 511;
        return A + ((size_t)(bb * 2050 + t5 + tap) * 512 + k2);
    } else {
        return A + ((size_t)(m0 + r) * K + kk);
    }
}

// ---------------------------------------------------------------------------
// bf16 MFMA GEMM (round-14 proven).
//  BM=64,BN=32 : 128 thr, 2 waves row-split (N=512 shapes, grid 1024).
//  BM=128,BN=64: 256 thr, 4 waves 2x2 (qkv/ffn1).
// ---------------------------------------------------------------------------
template<int MODE, int BM, int BN>
__global__ __launch_bounds__((BM == 64) ? 128 : 256) void gemm_mfma(
    const short* __restrict__ A, const short* __restrict__ Bw,
    const float* __restrict__ bias, const void* __restrict__ res,
    void* __restrict__ Cout, short* __restrict__ vTb, int K) {
    constexpr int NT  = (BM == 64) ? 128 : 256;
    constexpr int MF  = (BM == 64) ? 2 : 4;
    constexpr int NF  = 2;
    constexpr int ACH = (BM * 64 * 2) / (16 * NT);
    constexpr int BCH = (BN * 64 * 2) / (16 * NT);
    __shared__ short As[BM * 64];
    __shared__ short Bs[BN * 64];
    const int tid = threadIdx.x;
    const int w = tid >> 6, l = tid & 63;
    const int lr = l & 15, lc = l >> 4;
    const int wrb = (BM == 64) ? (w * 32) : ((w >> 1) * 64);
    const int wcb = (BM == 64) ? 0 : ((w & 1) * 32);
    const int m0 = blockIdx.x * BM, n0 = blockIdx.y * BN;
    f32x4 acc[MF][NF];
    #pragma unroll
    for (int mf = 0; mf < MF; mf++)
        #pragma unroll
        for (int nf = 0; nf < NF; nf++) acc[mf][nf] = (f32x4){0.f, 0.f, 0.f, 0.f};

    for (int k0 = 0; k0 < K; k0 += 64) {
        #pragma unroll
        for (int i = 0; i < ACH; i++) {
            int u = i * NT + tid, r = u >> 3, c = (u & 7) ^ (r & 7);
            gload16(a_ptr<MODE>(A, m0, r, k0 + c * 8, K), (char*)As + u * 16);
        }
        #pragma unroll
        for (int i = 0; i < BCH; i++) {
            int u = i * NT + tid, r = u >> 3, c = (u & 7) ^ (r & 7);
            gload16(Bw + ((size_t)(n0 + r) * K + k0 + c * 8), (char*)Bs + u * 16);
        }
        __syncthreads();
        bf16x8 af[MF][2], bfv[NF][2];
        #pragma unroll
        for (int mf = 0; mf < MF; mf++)
            #pragma unroll
            for (int ks = 0; ks < 2; ks++) {
                int rr = wrb + mf * 16 + lr;
                int cc = (ks * 4 + lc) ^ (rr & 7);
                af[mf][ks] = *(const bf16x8*)&As[rr * 64 + cc * 8];
            }
        #pragma unroll
        for (int nf = 0; nf < NF; nf++)
            #pragma unroll
            for (int ks = 0; ks < 2; ks++) {
                int rr = wcb + nf * 16 + lr;
                int cc = (ks * 4 + lc) ^ (rr & 7);
                bfv[nf][ks] = *(const bf16x8*)&Bs[rr * 64 + cc * 8];
            }
        __builtin_amdgcn_s_setprio(1);
        #pragma unroll
        for (int nf = 0; nf < NF; nf++)
            #pragma unroll
            for (int ks = 0; ks < 2; ks++)
                #pragma unroll
                for (int mf = 0; mf < MF; mf++)
                    acc[mf][nf] = __builtin_amdgcn_mfma_f32_16x16x32_bf16(
                        af[mf][ks], bfv[nf][ks], acc[mf][nf], 0, 0, 0);
        __builtin_amdgcn_s_setprio(0);
        __syncthreads();
    }
    // epilogue (all activation outputs bf16)
    #pragma unroll
    for (int mf = 0; mf < MF; mf++) {
        int row0 = m0 + wrb + mf * 16 + lc * 4;
        #pragma unroll
        for (int nf = 0; nf < NF; nf++) {
            int col = n0 + wcb + nf * 16 + lr;
            float bv = bias[col];
            if constexpr (MODE == M_CONV) {
                short* Cb = (short*)Cout;
                const float* rf = (const float*)res;
                #pragma unroll
                for (int rg = 0; rg < 4; rg++) {
                    size_t off = (size_t)(row0 + rg) * 512 + col;
                    Cb[off] = f2bf(acc[mf][nf][rg] + bv + rf[off]);
                }
            } else if constexpr (MODE == M_PROJ || MODE == M_FFN2) {
                short* Cb = (short*)Cout;
                const short* rb = (const short*)res;
                #pragma unroll
                for (int rg = 0; rg < 4; rg++) {
                    size_t off = (size_t)(row0 + rg) * 512 + col;
                    Cb[off] = f2bf(acc[mf][nf][rg] + bv + bf2f(rb[off]));
                }
            } else if constexpr (MODE == M_FFN1) {
                short* Cb = (short*)Cout;
                #pragma unroll
                for (int rg = 0; rg < 4; rg++)
                    Cb[(size_t)(row0 + rg) * 1024 + col] =
                        f2bf(fmaxf(acc[mf][nf][rg] + bv, 0.f));
            } else {  // M_QKV
                short* Cb = (short*)Cout;
                float v[4];
                #pragma unroll
                for (int rg = 0; rg < 4; rg++) {
                    v[rg] = acc[mf][nf][rg] + bv;
                    float wv = (col < 512) ? v[rg] * QSC : v[rg];
                    Cb[(size_t)(row0 + rg) * 1536 + col] = f2bf(wv);
                }
                if (col >= 1024) {  // V transposed: vT[bh][d][t]
                    int vc = col - 1024, hh = vc >> 6, dd = vc & 63;
                    int bb = row0 >> 11, t5 = row0 & 2047;
                    short4v pk = {f2bf(v[0]), f2bf(v[1]), f2bf(v[2]), f2bf(v[3])};
                    *(short4v*)&vTb[((size_t)((bb << 3) + hh) * 64 + dd) * 2048 + t5] = pk;
                }
            }
        }
    }
}

// ---------------------------------------------------------------------------
// Flash attention, QBLK=128 4-way KV-split. Grid 1024 = (qh 16 | par 4 |
// bh 16), L = ((15-qh)<<6)|(par<<4)|bh. 4 waves x 32 Q-rows; per superstep
// each staged K/V tile feeds 2x16-row sub-tiles sequentially (wave-private
// P buffer reused, no extra barrier) -> 36 MFMA per barrier (2x round-14).
// Supersteps halve; staging traffic per FLOP halves. exp2-domain softmax,
// MFMA row-sum, K/V dbuf, one barrier/superstep.
// Fully-masked-tile partials carry m=-1e30 and are zero-weighted in merge;
// in-block garbage is flushed by the defer-max rescale (alpha=0).
// ---------------------------------------------------------------------------
__global__ __launch_bounds__(256) void attn_part(const short* __restrict__ qkvb,
                                                 const short* __restrict__ vTb,
                                                 short* __restrict__ pO,
                                                 float* __restrict__ pML) {
    __shared__ short SM[20992];  // K dbuf [2][4096] @0 | V dbuf [2][4096] @8192 | P @16384
    __bf16* SMb = (__bf16*)SM;
    const int tid = threadIdx.x;
    const int w = tid >> 6, l = tid & 63;
    const int lr = l & 15, lc = l >> 4;
    const int L = blockIdx.x;
    const int bh = L & 15;
    const int par = (L >> 4) & 3;
    const int qh = 15 - (L >> 6);
    const int b = bh >> 3, h = bh & 7;
    const int q0 = qh * 128;
    const int pbase = 16384 + w * (16 * 72);
    const int top = 2 * qh + 1;
    const int ntiles = (top >= par) ? ((top - par) >> 2) + 1 : 0;

    // prologue: Q (128x64) bounced through the K/V-dbuf region
    #pragma unroll
    for (int i = 0; i < 4; i++) {
        int u = i * 256 + tid, r = u >> 3, c = (u & 7) ^ (r & 7);
        gload16(qkvb + ((size_t)(b * 2048 + q0 + r) * 1536 + h * 64 + c * 8),
                (char*)&SM[0] + u * 16);
    }
    __syncthreads();
    bf16x8 aq[2][2];
    #pragma unroll
    for (int mf = 0; mf < 2; mf++)
        #pragma unroll
        for (int ks = 0; ks < 2; ks++) {
            int rr = w * 32 + mf * 16 + lr;
            int cc = (lc + 4 * ks) ^ (rr & 7);
            aq[mf][ks] = *(const bf16x8*)&SM[rr * 64 + cc * 8];
        }
    __syncthreads();   // all waves done reading Q; region becomes K/V buf 0
    if (ntiles > 0) {
        #pragma unroll
        for (int i = 0; i < 2; i++) {
            int u = i * 256 + tid, r = u >> 3, c = (u & 7) ^ (r & 7);
            gload16(qkvb + ((size_t)(b * 2048 + par * 64 + r) * 1536 + 512 + h * 64 + c * 8),
                    (char*)&SM[0] + u * 16);
            gload16(vTb + ((size_t)(bh * 64 + r) * 2048 + par * 64 + c * 8),
                    (char*)&SM[8192] + u * 16);
        }
    }
    __syncthreads();   // K0/V0 ready

    bf16x8 onesf;
    #pragma unroll
    for (int i = 0; i < 8; i++) onesf[i] = (__bf16)1.0f;

    f32x4 o[2][4], lacc[2];
    float mst[2][4];
    #pragma unroll
    for (int mf = 0; mf < 2; mf++) {
        lacc[mf] = (f32x4){0.f, 0.f, 0.f, 0.f};
        #pragma unroll
        for (int nf = 0; nf < 4; nf++) o[mf][nf] = (f32x4){0.f, 0.f, 0.f, 0.f};
        #pragma unroll
        for (int rg = 0; rg < 4; rg++) mst[mf][rg] = -1e30f;
    }

    for (int s = 0; s < ntiles; s++) {
        const int kt = par + 4 * s;
        const int cur = s & 1;
        if (s + 1 < ntiles) {
            int ktn = kt + 4, nb = (cur ^ 1) * 4096;
            #pragma unroll
            for (int i = 0; i < 2; i++) {
                int u = i * 256 + tid, r = u >> 3, c = (u & 7) ^ (r & 7);
                gload16(qkvb + ((size_t)(b * 2048 + ktn * 64 + r) * 1536 + 512 + h * 64 + c * 8),
                        (char*)&SM[nb] + u * 16);
                gload16(vTb + ((size_t)(bh * 64 + r) * 2048 + ktn * 64 + c * 8),
                        (char*)&SM[8192 + nb] + u * 16);
            }
        }
        const bool crossing = (kt >= 2 * qh);   // tiles 2qh, 2qh+1 need masks
        #pragma unroll
        for (int mf = 0; mf < 2; mf++) {
            // ---- S = Q @ K^T (log2 domain) ----
            f32x4 s4[4];
            #pragma unroll
            for (int nf = 0; nf < 4; nf++) s4[nf] = (f32x4){0.f, 0.f, 0.f, 0.f};
            __builtin_amdgcn_s_setprio(1);
            #pragma unroll
            for (int nf = 0; nf < 4; nf++) {
                #pragma unroll
                for (int ks = 0; ks < 2; ks++) {
                    int rr = nf * 16 + lr;
                    int cc = (lc + 4 * ks) ^ (rr & 7);
                    bf16x8 bk = *(const bf16x8*)&SM[cur * 4096 + rr * 64 + cc * 8];
                    s4[nf] = __builtin_amdgcn_mfma_f32_16x16x32_bf16(aq[mf][ks], bk, s4[nf], 0, 0, 0);
                }
            }
            __builtin_amdgcn_s_setprio(0);
            // ---- causal mask (crossing tiles only) ----
            if (crossing) {
                int rowb = q0 + w * 32 + mf * 16 + lc * 4;
                #pragma unroll
                for (int nf = 0; nf < 4; nf++) {
                    int colg = kt * 64 + nf * 16 + lr;
                    #pragma unroll
                    for (int rg = 0; rg < 4; rg++)
                        if (colg > rowb + rg) s4[nf][rg] = -1e30f;
                }
            }
            // ---- online softmax (exp2-domain) with defer-max ----
            float rm[4];
            int ok = 1;
            #pragma unroll
            for (int rg = 0; rg < 4; rg++) {
                float m_ = fmaxf(fmaxf(s4[0][rg], s4[1][rg]), fmaxf(s4[2][rg], s4[3][rg]));
                m_ = fmaxf(m_, __shfl_xor(m_, 1));
                m_ = fmaxf(m_, __shfl_xor(m_, 2));
                m_ = fmaxf(m_, __shfl_xor(m_, 4));
                m_ = fmaxf(m_, __shfl_xor(m_, 8));
                rm[rg] = m_;
                ok &= (m_ <= mst[mf][rg] + 11.5f);
            }
            if (!__all(ok)) {
                #pragma unroll
                for (int rg = 0; rg < 4; rg++) {
                    float mn = fmaxf(mst[mf][rg], rm[rg]);
                    float alpha = exp2f(mst[mf][rg] - mn);
                    mst[mf][rg] = mn;
                    lacc[mf][rg] *= alpha;
                    #pragma unroll
                    for (int nf = 0; nf < 4; nf++) o[mf][nf][rg] *= alpha;
                }
            }
            #pragma unroll
            for (int rg = 0; rg < 4; rg++) {
                int prow = pbase + (lc * 4 + rg) * 72;
                SMb[prow      + lr] = (__bf16)exp2f(s4[0][rg] - mst[mf][rg]);
                SMb[prow + 16 + lr] = (__bf16)exp2f(s4[1][rg] - mst[mf][rg]);
                SMb[prow + 32 + lr] = (__bf16)exp2f(s4[2][rg] - mst[mf][rg]);
                SMb[prow + 48 + lr] = (__bf16)exp2f(s4[3][rg] - mst[mf][rg]);
            }
            // ---- O += P @ V ; l += P @ 1 (wave-private P; no barrier) ----
            bf16x8 pa[2];
            #pragma unroll
            for (int ks = 0; ks < 2; ks++)
                pa[ks] = *(const bf16x8*)&SM[pbase + lr * 72 + ks * 32 + lc * 8];
            __builtin_amdgcn_s_setprio(1);
            #pragma unroll
            for (int ks = 0; ks < 2; ks++)
                lacc[mf] = __builtin_amdgcn_mfma_f32_16x16x32_bf16(pa[ks], onesf, lacc[mf], 0, 0, 0);
            #pragma unroll
            for (int nf = 0; nf < 4; nf++) {
                #pragma unroll
                for (int ks = 0; ks < 2; ks++) {
                    int rr = nf * 16 + lr;
                    int cc = (lc + 4 * ks) ^ (rr & 7);
                    bf16x8 bv = *(const bf16x8*)&SM[8192 + cur * 4096 + rr * 64 + cc * 8];
                    o[mf][nf] = __builtin_amdgcn_mfma_f32_16x16x32_bf16(pa[ks], bv, o[mf][nf], 0, 0, 0);
                }
            }
            __builtin_amdgcn_s_setprio(0);
        }
        __syncthreads();  // all reads of cur done; next iter overwrites cur
    }

    // ---- write partials (init values give zeros/m=-1e30 for empty blocks) ----
    size_t ob = (size_t)L * 8192;
    #pragma unroll
    for (int mf = 0; mf < 2; mf++) {
        #pragma unroll
        for (int nf = 0; nf < 4; nf++) {
            #pragma unroll
            for (int rg = 0; rg < 4; rg++) {
                int rw = w * 32 + mf * 16 + lc * 4 + rg;
                pO[ob + rw * 64 + nf * 16 + lr] = f2bf(o[mf][nf][rg]);
            }
        }
        if (lr == 0) {
            #pragma unroll
            for (int rg = 0; rg < 4; rg++) {
                int rw = w * 32 + mf * 16 + lc * 4 + rg;
                pML[(size_t)L * 256 + rw]       = mst[mf][rg];
                pML[(size_t)L * 256 + 128 + rw] = lacc[mf][rg];
            }
        }
    }
}

// ---------------------------------------------------------------------------
// 4-way cross-block LSE merge: 512 blocks = (qt 32, bh 16); each handles 64
// rows = half of a 128-row partial block. Writes bf16 attnout.
// ---------------------------------------------------------------------------
__global__ __launch_bounds__(256) void attn_merge(const short* __restrict__ pO,
                                                  const float* __restrict__ pML,
                                                  short* __restrict__ aout) {
    int U = blockIdx.x;
    int bh = U & 15, qt = U >> 4;
    int b = bh >> 3, h = bh & 7, q0 = qt * 64;
    int qh = qt >> 1, rowofs = (qt & 1) * 64;
    int Lb = ((15 - qh) << 6) | bh;
    int t = threadIdx.x;
    int r = t >> 2, cs = (t & 3) * 16;
    int rr = rowofs + r;
    float m[4], lv[4];
    #pragma unroll
    for (int pp = 0; pp < 4; pp++) {
        m[pp]  = pML[(size_t)(Lb | (pp << 4)) * 256 + rr];
        lv[pp] = pML[(size_t)(Lb | (pp << 4)) * 256 + 128 + rr];
    }
    float mn = fmaxf(fmaxf(m[0], m[1]), fmaxf(m[2], m[3]));
    float a[4], den = 0.f;
    #pragma unroll
    for (int pp = 0; pp < 4; pp++) { a[pp] = exp2f(m[pp] - mn); den += lv[pp] * a[pp]; }
    float inv = 1.f / den;
    #pragma unroll
    for (int half = 0; half < 2; half++) {
        int c0 = cs + half * 8;
        float accv[8];
        #pragma unroll
        for (int j = 0; j < 8; j++) accv[j] = 0.f;
        #pragma unroll
        for (int pp = 0; pp < 4; pp++) {
            short8v ov = *(const short8v*)&pO[(size_t)(Lb | (pp << 4)) * 8192 + rr * 64 + c0];
            #pragma unroll
            for (int j = 0; j < 8; j++) accv[j] += bf2f(ov[j]) * a[pp];
        }
        short8v res;
        #pragma unroll
        for (int j = 0; j < 8; j++) res[j] = f2bf(accv[j] * inv);
        *(short8v*)&aout[(size_t)(b * 2048 + q0 + r) * 512 + h * 64 + c0] = res;
    }
}

// ---------------------------------------------------------------------------
extern "C" void kernel_launch(void* const* d_in, const int* in_sizes, int n_in,
                              void* d_out, int out_size, void* d_ws, size_t ws_size,
                              hipStream_t stream) {
    const float* x      = (const float*)d_in[0];
    const float* conv_w = (const float*)d_in[1];
    const float* conv_b = (const float*)d_in[2];
    const float* g1     = (const float*)d_in[3];
    const float* b1     = (const float*)d_in[4];
    const float* qkv_w  = (const float*)d_in[5];
    const float* qkv_b  = (const float*)d_in[6];
    const float* proj_w = (const float*)d_in[7];
    const float* proj_b = (const float*)d_in[8];
    const float* g2     = (const float*)d_in[9];
    const float* b2     = (const float*)d_in[10];
    const float* ffn_w1 = (const float*)d_in[11];
    const float* ffn_b1 = (const float*)d_in[12];
    const float* ffn_w2 = (const float*)d_in[13];
    const float* ffn_b2 = (const float*)d_in[14];
    const float* g3     = (const float*)d_in[15];
    const float* b3     = (const float*)d_in[16];
    float* out = (float*)d_out;

    char* p = (char*)d_ws;
    short* cwT   = (short*)p;  p += 786432 * 2;
    short* qkvT  = (short*)p;  p += 786432 * 2;
    short* projT = (short*)p;  p += 262144 * 2;
    short* f1T   = (short*)p;  p += 524288 * 2;
    short* f2T   = (short*)p;  p += 524288 * 2;
    short* xpad  = (short*)p;  p += 2099200 * 2;
    short* yb    = (short*)p;  p += 2097152 * 2;   // bf16 pre-LN activations
    short* x1b   = (short*)p;  p += 2097152 * 2;   // LN1 out (qkv A + proj res)
    short* qkvb  = (short*)p;  p += 6291456 * 2;
    short* vTb   = (short*)p;  p += 2097152 * 2;
    short* pO    = (short*)p;  p += 8388608 * 2;   // 1024 x 128 x 64 bf16 partial O
    float* pML   = (float*)p;  p += 262144 * 4;    // 1024 x (m[128] | l[128])
    // aliases of dead buffers:
    short* x2b     = x1b;   // x1b dead after proj epilogue (its last reader)
    short* hb      = qkvb;  // qkvb dead after attention
    short* attnout = xpad;  // xpad dead after conv GEMM

    prep_all<<<4097, 256, 0, stream>>>(conv_w, x, qkv_w, proj_w, ffn_w1, ffn_w2,
                                       cwT, xpad, qkvT, projT, f1T, f2T);
    gemm_mfma<M_CONV, 64, 32><<<dim3(64, 16), 128, 0, stream>>>(
        xpad, cwT, conv_b, x, yb, nullptr, 1536);
    ln_row<<<512, 512, 0, stream>>>(yb, g1, b1, nullptr, x1b);
    gemm_mfma<M_QKV, 128, 64><<<dim3(32, 24), 256, 0, stream>>>(
        x1b, qkvT, qkv_b, nullptr, qkvb, vTb, 512);
    attn_part<<<1024, 256, 0, stream>>>(qkvb, vTb, pO, pML);
    attn_merge<<<512, 256, 0, stream>>>(pO, pML, attnout);
    gemm_mfma<M_PROJ, 64, 32><<<dim3(64, 16), 128, 0, stream>>>(
        attnout, projT, proj_b, x1b, yb, nullptr, 512);
    ln_row<<<512, 512, 0, stream>>>(yb, g2, b2, nullptr, x2b);
    gemm_mfma<M_FFN1, 128, 64><<<dim3(32, 16), 256, 0, stream>>>(
        x2b, f1T, ffn_b1, nullptr, hb, nullptr, 512);
    gemm_mfma<M_FFN2, 64, 32><<<dim3(64, 16), 128, 0, stream>>>(
        hb, f2T, ffn_b2, x2b, yb, nullptr, 1024);
    ln_row<<<512, 512, 0, stream>>>(yb, g3, b3, out, nullptr);
}

// Round 16
// 118.094 us; speedup vs baseline: 1.0442x; 1.0442x over previous
//
#include <hip/hip_runtime.h>
#include <hip/hip_bf16.h>

#define TT 2048
#define QSC 0.18033688011112042f   // 0.125 * log2(e)

typedef __attribute__((ext_vector_type(4))) float f32x4;
typedef __attribute__((ext_vector_type(8))) __bf16 bf16x8;
typedef __attribute__((ext_vector_type(4))) short short4v;
typedef __attribute__((ext_vector_type(8))) short short8v;

enum { M_CONV = 0, M_QKV = 1, M_PROJ = 2, M_FFN1 = 3, M_FFN2 = 4 };

__device__ __forceinline__ void gload16(const void* g, void* l) {
    __builtin_amdgcn_global_load_lds(
        (__attribute__((address_space(1))) void*)g,
        (__attribute__((address_space(3))) void*)l, 16, 0, 0);
}

__device__ __forceinline__ short f2bf(float f) {
    unsigned u = __float_as_uint(f);
    u = (u + 0x7fffu + ((u >> 16) & 1u)) >> 16;
    return (short)u;
}

__device__ __forceinline__ float bf2f(short s) {
    unsigned u = ((unsigned)(unsigned short)s) << 16;
    return __uint_as_float(u);
}

// ---------------------------------------------------------------------------
// One prep kernel, fully coalesced (round-13 proven).
// ---------------------------------------------------------------------------
__global__ __launch_bounds__(256) void prep_all(
    const float* __restrict__ conv_w, const float* __restrict__ x,
    const float* __restrict__ qkv_w, const float* __restrict__ proj_w,
    const float* __restrict__ f1w, const float* __restrict__ f2w,
    short* __restrict__ cwT, short* __restrict__ xpad,
    short* __restrict__ qkvT, short* __restrict__ projT,
    short* __restrict__ f1T, short* __restrict__ f2T) {
    if (blockIdx.x < 2048) {
        int t = blockIdx.x;
        const float* src; short* dst; int K, N, lt;
        if (t < 768)       { src = qkv_w;  dst = qkvT;  K = 512;  N = 1536; lt = t; }
        else if (t < 1024) { src = proj_w; dst = projT; K = 512;  N = 512;  lt = t - 768; }
        else if (t < 1536) { src = f1w;    dst = f1T;   K = 512;  N = 1024; lt = t - 1024; }
        else               { src = f2w;    dst = f2T;   K = 1024; N = 512;  lt = t - 1536; }
        int ntn = N >> 5;
        int kt = lt / ntn, nt = lt - kt * ntn;
        int k0 = kt * 32, n0 = nt * 32;
        __shared__ float tile[32][33];
        int c = threadIdx.x & 31, r = threadIdx.x >> 5;
        #pragma unroll
        for (int i = 0; i < 4; i++)
            tile[r + i * 8][c] = src[(size_t)(k0 + r + i * 8) * N + n0 + c];
        __syncthreads();
        #pragma unroll
        for (int i = 0; i < 4; i++)
            dst[(size_t)(n0 + r + i * 8) * K + k0 + c] = f2bf(tile[c][r + i * 8]);
        return;
    }
    if (blockIdx.x < 3072) {                  // conv_w OIH -> [o][tap*512+i]
        int oi = (blockIdx.x - 2048) * 256 + threadIdx.x;   // < 262144
        int o = oi >> 9, i = oi & 511;
        const float* s = conv_w + (size_t)oi * 3;
        #pragma unroll
        for (int tap = 0; tap < 3; tap++)
            cwT[(size_t)o * 1536 + tap * 512 + i] = f2bf(s[tap]);
        return;
    }
    int idx = (blockIdx.x - 3072) * 256 + threadIdx.x;      // < 262400
    int rp = idx >> 6, j = idx & 63;
    if (rp < 4100) {                          // x -> xpad [2][2050][512] bf16
        int bb = rp / 2050, rr = rp - bb * 2050;
        int t = rr - 2;
        short8v pk;
        if (t >= 0) {
            const float* xs = x + ((size_t)(bb << 11) + t) * 512 + j * 8;
            f32x4 a = *(const f32x4*)xs;
            f32x4 b2 = *(const f32x4*)(xs + 4);
            #pragma unroll
            for (int i = 0; i < 4; i++) { pk[i] = f2bf(a[i]); pk[i + 4] = f2bf(b2[i]); }
        } else {
            #pragma unroll
            for (int i = 0; i < 8; i++) pk[i] = 0;
        }
        *(short8v*)&xpad[(size_t)rp * 512 + j * 8] = pk;
    }
}

// ---------------------------------------------------------------------------
// Row LayerNorm, wave-per-row, bf16 input. 512 threads = 8 rows/block.
// ---------------------------------------------------------------------------
__global__ __launch_bounds__(512) void ln_row(const short* __restrict__ in,
                                              const float* __restrict__ g,
                                              const float* __restrict__ b,
                                              float* __restrict__ outf,
                                              short* __restrict__ outb) {
    int row = blockIdx.x * 8 + (threadIdx.x >> 6);
    int l = threadIdx.x & 63;
    short8v v = *(const short8v*)(in + (size_t)row * 512 + l * 8);
    float vf[8];
    float s = 0.f, ss = 0.f;
    #pragma unroll
    for (int i = 0; i < 8; i++) {
        vf[i] = bf2f(v[i]);
        s += vf[i]; ss += vf[i] * vf[i];
    }
    #pragma unroll
    for (int off = 1; off < 64; off <<= 1) {
        s  += __shfl_xor(s, off);
        ss += __shfl_xor(ss, off);
    }
    float mean = s * (1.f / 512);
    float var  = ss * (1.f / 512) - mean * mean;
    float rstd = rsqrtf(var + 1e-5f);
    f32x4 g0 = *(const f32x4*)(g + l * 8), g1 = *(const f32x4*)(g + l * 8 + 4);
    f32x4 b0 = *(const f32x4*)(b + l * 8), b1 = *(const f32x4*)(b + l * 8 + 4);
    float ov[8];
    #pragma unroll
    for (int i = 0; i < 4; i++) {
        ov[i]     = (vf[i]     - mean) * rstd * g0[i] + b0[i];
        ov[i + 4] = (vf[i + 4] - mean) * rstd * g1[i] + b1[i];
    }
    if (outf) {
        float* q = outf + (size_t)row * 512 + l * 8;
        *(f32x4*)q       = (f32x4){ov[0], ov[1], ov[2], ov[3]};
        *(f32x4*)(q + 4) = (f32x4){ov[4], ov[5], ov[6], ov[7]};
    }
    if (outb) {
        short8v pk;
        #pragma unroll
        for (int i = 0; i < 8; i++) pk[i] = f2bf(ov[i]);
        *(short8v*)(outb + (size_t)row * 512 + l * 8) = pk;
    }
}

// ---------------------------------------------------------------------------
// A-operand global address (handles conv's padded/3-tap layout)
// ---------------------------------------------------------------------------
template<int MODE>
__device__ __forceinline__ const short* a_ptr(const short* A, int m0, int r, int kk, int K) {
    if constexpr (MODE == M_CONV) {
        int row = m0 + r;
        int bb = row >> 11, t5 = row & 2047;
        int tap = kk >> 9, k2 = kk & 511;
        return A + ((size_t)(bb * 2050 + t5 + tap) * 512 + k2);
    } else {
        return A + ((size_t)(m0 + r) * K + kk);
    }
}

// ---------------------------------------------------------------------------
// bf16 MFMA GEMM.
//  BM=64,BN=32,BK=128 : 128 thr, 2 waves row-split, 32 MFMA/barrier
//                       (half the barrier-drains of BK=64), LDS 24KB,
//                       grid (64, N/32) -> 4 blocks/CU.
//  BM=128,BN=64,BK=64 : 256 thr, 4 waves 2x2 (qkv/ffn1, proven).
// gload_lds staging, single LDS buffer, chunk-swizzle both sides.
// ---------------------------------------------------------------------------
template<int MODE, int BM, int BN, int BK>
__global__ __launch_bounds__((BM == 64) ? 128 : 256) void gemm_mfma(
    const short* __restrict__ A, const short* __restrict__ Bw,
    const float* __restrict__ bias, const void* __restrict__ res,
    void* __restrict__ Cout, short* __restrict__ vTb, int K) {
    constexpr int NT  = (BM == 64) ? 128 : 256;
    constexpr int MF  = (BM == 64) ? 2 : 4;
    constexpr int NF  = 2;
    constexpr int KCH = BK / 32;                     // MFMA k-substeps
    constexpr int CPR = BK / 8;                      // 16B chunks per row
    constexpr int CSH = (BK == 64) ? 3 : 4;          // log2(CPR)
    constexpr int CMSK = CPR - 1;
    constexpr int ACH = (BM * BK * 2) / (16 * NT);
    constexpr int BCH = (BN * BK * 2) / (16 * NT);
    __shared__ short As[BM * BK];
    __shared__ short Bs[BN * BK];
    const int tid = threadIdx.x;
    const int w = tid >> 6, l = tid & 63;
    const int lr = l & 15, lc = l >> 4;
    const int wrb = (BM == 64) ? (w * 32) : ((w >> 1) * 64);
    const int wcb = (BM == 64) ? 0 : ((w & 1) * 32);
    const int m0 = blockIdx.x * BM, n0 = blockIdx.y * BN;
    f32x4 acc[MF][NF];
    #pragma unroll
    for (int mf = 0; mf < MF; mf++)
        #pragma unroll
        for (int nf = 0; nf < NF; nf++) acc[mf][nf] = (f32x4){0.f, 0.f, 0.f, 0.f};

    for (int k0 = 0; k0 < K; k0 += BK) {
        #pragma unroll
        for (int i = 0; i < ACH; i++) {
            int u = i * NT + tid, r = u >> CSH, c = (u & CMSK) ^ (r & 7);
            gload16(a_ptr<MODE>(A, m0, r, k0 + c * 8, K), (char*)As + u * 16);
        }
        #pragma unroll
        for (int i = 0; i < BCH; i++) {
            int u = i * NT + tid, r = u >> CSH, c = (u & CMSK) ^ (r & 7);
            gload16(Bw + ((size_t)(n0 + r) * K + k0 + c * 8), (char*)Bs + u * 16);
        }
        __syncthreads();
        bf16x8 af[MF][KCH], bfv[NF][KCH];
        #pragma unroll
        for (int mf = 0; mf < MF; mf++)
            #pragma unroll
            for (int ks = 0; ks < KCH; ks++) {
                int rr = wrb + mf * 16 + lr;
                int cc = (ks * 4 + lc) ^ (rr & 7);
                af[mf][ks] = *(const bf16x8*)&As[rr * BK + cc * 8];
            }
        #pragma unroll
        for (int nf = 0; nf < NF; nf++)
            #pragma unroll
            for (int ks = 0; ks < KCH; ks++) {
                int rr = wcb + nf * 16 + lr;
                int cc = (ks * 4 + lc) ^ (rr & 7);
                bfv[nf][ks] = *(const bf16x8*)&Bs[rr * BK + cc * 8];
            }
        __builtin_amdgcn_s_setprio(1);
        #pragma unroll
        for (int nf = 0; nf < NF; nf++)
            #pragma unroll
            for (int ks = 0; ks < KCH; ks++)
                #pragma unroll
                for (int mf = 0; mf < MF; mf++)
                    acc[mf][nf] = __builtin_amdgcn_mfma_f32_16x16x32_bf16(
                        af[mf][ks], bfv[nf][ks], acc[mf][nf], 0, 0, 0);
        __builtin_amdgcn_s_setprio(0);
        __syncthreads();
    }
    // epilogue (all activation outputs bf16)
    #pragma unroll
    for (int mf = 0; mf < MF; mf++) {
        int row0 = m0 + wrb + mf * 16 + lc * 4;
        #pragma unroll
        for (int nf = 0; nf < NF; nf++) {
            int col = n0 + wcb + nf * 16 + lr;
            float bv = bias[col];
            if constexpr (MODE == M_CONV) {
                short* Cb = (short*)Cout;
                const float* rf = (const float*)res;
                #pragma unroll
                for (int rg = 0; rg < 4; rg++) {
                    size_t off = (size_t)(row0 + rg) * 512 + col;
                    Cb[off] = f2bf(acc[mf][nf][rg] + bv + rf[off]);
                }
            } else if constexpr (MODE == M_PROJ || MODE == M_FFN2) {
                short* Cb = (short*)Cout;
                const short* rb = (const short*)res;
                #pragma unroll
                for (int rg = 0; rg < 4; rg++) {
                    size_t off = (size_t)(row0 + rg) * 512 + col;
                    Cb[off] = f2bf(acc[mf][nf][rg] + bv + bf2f(rb[off]));
                }
            } else if constexpr (MODE == M_FFN1) {
                short* Cb = (short*)Cout;
                #pragma unroll
                for (int rg = 0; rg < 4; rg++)
                    Cb[(size_t)(row0 + rg) * 1024 + col] =
                        f2bf(fmaxf(acc[mf][nf][rg] + bv, 0.f));
            } else {  // M_QKV
                short* Cb = (short*)Cout;
                float v[4];
                #pragma unroll
                for (int rg = 0; rg < 4; rg++) {
                    v[rg] = acc[mf][nf][rg] + bv;
                    float wv = (col < 512) ? v[rg] * QSC : v[rg];
                    Cb[(size_t)(row0 + rg) * 1536 + col] = f2bf(wv);
                }
                if (col >= 1024) {  // V transposed: vT[bh][d][t]
                    int vc = col - 1024, hh = vc >> 6, dd = vc & 63;
                    int bb = row0 >> 11, t5 = row0 & 2047;
                    short4v pk = {f2bf(v[0]), f2bf(v[1]), f2bf(v[2]), f2bf(v[3])};
                    *(short4v*)&vTb[((size_t)((bb << 3) + hh) * 64 + dd) * 2048 + t5] = pk;
                }
            }
        }
    }
}

// ---------------------------------------------------------------------------
// Flash attention, 4-way KV-split partial kernel (round-14 proven, reverted).
// Grid 2048 = (qt 32 | par 4 | bh 16), L = ((31-qt)<<6)|(par<<4)|bh.
// exp2-domain softmax, MFMA row-sum, K/V dbuf, one barrier/superstep.
// ---------------------------------------------------------------------------
__global__ __launch_bounds__(256) void attn_part(const short* __restrict__ qkvb,
                                                 const short* __restrict__ vTb,
                                                 short* __restrict__ pO,
                                                 float* __restrict__ pML) {
    __shared__ short SM[20992];  // K dbuf [2][4096] @0 | V dbuf [2][4096] @8192 | P/Q @16384
    __bf16* SMb = (__bf16*)SM;
    const int tid = threadIdx.x;
    const int w = tid >> 6, l = tid & 63;
    const int lr = l & 15, lc = l >> 4;
    const int L = blockIdx.x;
    const int bh = L & 15;
    const int par = (L >> 4) & 3;
    const int qt = 31 - (L >> 6);
    const int b = bh >> 3, h = bh & 7;
    const int qr = w * 16, q0 = qt * 64;
    const int pbase = 16384 + w * (16 * 72);
    const int ntiles = (qt >= par) ? ((qt - par) >> 2) + 1 : 0;

    #pragma unroll
    for (int i = 0; i < 2; i++) {
        int u = i * 256 + tid, r = u >> 3, c = (u & 7) ^ (r & 7);
        gload16(qkvb + ((size_t)(b * 2048 + q0 + r) * 1536 + h * 64 + c * 8),
                (char*)&SM[16384] + u * 16);
        if (ntiles > 0) {
            gload16(qkvb + ((size_t)(b * 2048 + par * 64 + r) * 1536 + 512 + h * 64 + c * 8),
                    (char*)&SM[0] + u * 16);
            gload16(vTb + ((size_t)(bh * 64 + r) * 2048 + par * 64 + c * 8),
                    (char*)&SM[8192] + u * 16);
        }
    }
    __syncthreads();
    bf16x8 aq[2];
    #pragma unroll
    for (int ks = 0; ks < 2; ks++) {
        int rr = qr + lr;
        int cc = (lc + 4 * ks) ^ (rr & 7);
        aq[ks] = *(const bf16x8*)&SM[16384 + rr * 64 + cc * 8];
    }
    __syncthreads();   // Q reads done; region becomes Ps

    bf16x8 onesf;
    #pragma unroll
    for (int i = 0; i < 8; i++) onesf[i] = (__bf16)1.0f;

    f32x4 o[4], lacc;
    float mst[4];
    #pragma unroll
    for (int nf = 0; nf < 4; nf++) o[nf] = (f32x4){0.f, 0.f, 0.f, 0.f};
    lacc = (f32x4){0.f, 0.f, 0.f, 0.f};
    #pragma unroll
    for (int rg = 0; rg < 4; rg++) mst[rg] = -1e30f;

    for (int s = 0; s < ntiles; s++) {
        const int kt = par + 4 * s;
        const int cur = s & 1;
        if (s + 1 < ntiles) {
            int ktn = kt + 4, nb = (cur ^ 1) * 4096;
            #pragma unroll
            for (int i = 0; i < 2; i++) {
                int u = i * 256 + tid, r = u >> 3, c = (u & 7) ^ (r & 7);
                gload16(qkvb + ((size_t)(b * 2048 + ktn * 64 + r) * 1536 + 512 + h * 64 + c * 8),
                        (char*)&SM[nb] + u * 16);
                gload16(vTb + ((size_t)(bh * 64 + r) * 2048 + ktn * 64 + c * 8),
                        (char*)&SM[8192 + nb] + u * 16);
            }
        }
        // ---- S = Q @ K^T (log2 domain) ----
        f32x4 s4[4];
        #pragma unroll
        for (int nf = 0; nf < 4; nf++) s4[nf] = (f32x4){0.f, 0.f, 0.f, 0.f};
        __builtin_amdgcn_s_setprio(1);
        #pragma unroll
        for (int nf = 0; nf < 4; nf++) {
            #pragma unroll
            for (int ks = 0; ks < 2; ks++) {
                int rr = nf * 16 + lr;
                int cc = (lc + 4 * ks) ^ (rr & 7);
                bf16x8 bk = *(const bf16x8*)&SM[cur * 4096 + rr * 64 + cc * 8];
                s4[nf] = __builtin_amdgcn_mfma_f32_16x16x32_bf16(aq[ks], bk, s4[nf], 0, 0, 0);
            }
        }
        __builtin_amdgcn_s_setprio(0);
        // ---- online softmax (exp2-domain) with defer-max ----
        const bool diag = (kt == qt);
        if (diag) {
            #pragma unroll
            for (int nf = 0; nf < 4; nf++)
                #pragma unroll
                for (int rg = 0; rg < 4; rg++)
                    if (nf * 16 + lr > qr + lc * 4 + rg) s4[nf][rg] = -1e30f;
        }
        float rm[4];
        int ok = 1;
        #pragma unroll
        for (int rg = 0; rg < 4; rg++) {
            float m_ = fmaxf(fmaxf(s4[0][rg], s4[1][rg]), fmaxf(s4[2][rg], s4[3][rg]));
            m_ = fmaxf(m_, __shfl_xor(m_, 1));
            m_ = fmaxf(m_, __shfl_xor(m_, 2));
            m_ = fmaxf(m_, __shfl_xor(m_, 4));
            m_ = fmaxf(m_, __shfl_xor(m_, 8));
            rm[rg] = m_;
            ok &= (m_ <= mst[rg] + 11.5f);
        }
        if (!__all(ok)) {
            #pragma unroll
            for (int rg = 0; rg < 4; rg++) {
                float mn = fmaxf(mst[rg], rm[rg]);
                float alpha = exp2f(mst[rg] - mn);
                mst[rg] = mn;
                lacc[rg] *= alpha;
                #pragma unroll
                for (int nf = 0; nf < 4; nf++) o[nf][rg] *= alpha;
            }
        }
        #pragma unroll
        for (int rg = 0; rg < 4; rg++) {
            int prow = pbase + (lc * 4 + rg) * 72;
            SMb[prow      + lr] = (__bf16)exp2f(s4[0][rg] - mst[rg]);
            SMb[prow + 16 + lr] = (__bf16)exp2f(s4[1][rg] - mst[rg]);
            SMb[prow + 32 + lr] = (__bf16)exp2f(s4[2][rg] - mst[rg]);
            SMb[prow + 48 + lr] = (__bf16)exp2f(s4[3][rg] - mst[rg]);
        }
        // ---- O += P @ V ; l += P @ 1 ----
        bf16x8 pa[2];
        #pragma unroll
        for (int ks = 0; ks < 2; ks++)
            pa[ks] = *(const bf16x8*)&SM[pbase + lr * 72 + ks * 32 + lc * 8];
        __builtin_amdgcn_s_setprio(1);
        #pragma unroll
        for (int ks = 0; ks < 2; ks++)
            lacc = __builtin_amdgcn_mfma_f32_16x16x32_bf16(pa[ks], onesf, lacc, 0, 0, 0);
        #pragma unroll
        for (int nf = 0; nf < 4; nf++) {
            #pragma unroll
            for (int ks = 0; ks < 2; ks++) {
                int rr = nf * 16 + lr;
                int cc = (lc + 4 * ks) ^ (rr & 7);
                bf16x8 bv = *(const bf16x8*)&SM[8192 + cur * 4096 + rr * 64 + cc * 8];
                o[nf] = __builtin_amdgcn_mfma_f32_16x16x32_bf16(pa[ks], bv, o[nf], 0, 0, 0);
            }
        }
        __builtin_amdgcn_s_setprio(0);
        __syncthreads();
    }

    // ---- write partials ----
    size_t ob = (size_t)L * 4096;
    #pragma unroll
    for (int nf = 0; nf < 4; nf++) {
        #pragma unroll
        for (int rg = 0; rg < 4; rg++) {
            int rw = qr + lc * 4 + rg;
            pO[ob + rw * 64 + nf * 16 + lr] = (ntiles > 0) ? f2bf(o[nf][rg]) : (short)0;
        }
    }
    if (lr == 0) {
        #pragma unroll
        for (int rg = 0; rg < 4; rg++) {
            int rw = qr + lc * 4 + rg;
            pML[(size_t)L * 128 + rw]      = (ntiles > 0) ? mst[rg] : -1e30f;
            pML[(size_t)L * 128 + 64 + rw] = (ntiles > 0) ? lacc[rg] : 0.f;
        }
    }
}

// ---------------------------------------------------------------------------
// 4-way cross-block LSE merge (round-14 proven).
// ---------------------------------------------------------------------------
__global__ __launch_bounds__(256) void attn_merge(const short* __restrict__ pO,
                                                  const float* __restrict__ pML,
                                                  short* __restrict__ aout) {
    int U = blockIdx.x;
    int bh = U & 15, qt = U >> 4;
    int b = bh >> 3, h = bh & 7, q0 = qt * 64;
    int Lb = ((31 - qt) << 6) | bh;
    int t = threadIdx.x;
    int r = t >> 2, cs = (t & 3) * 16;
    float m[4], lv[4];
    #pragma unroll
    for (int pp = 0; pp < 4; pp++) {
        m[pp]  = pML[(size_t)(Lb | (pp << 4)) * 128 + r];
        lv[pp] = pML[(size_t)(Lb | (pp << 4)) * 128 + 64 + r];
    }
    float mn = fmaxf(fmaxf(m[0], m[1]), fmaxf(m[2], m[3]));
    float a[4], den = 0.f;
    #pragma unroll
    for (int pp = 0; pp < 4; pp++) { a[pp] = exp2f(m[pp] - mn); den += lv[pp] * a[pp]; }
    float inv = 1.f / den;
    #pragma unroll
    for (int half = 0; half < 2; half++) {
        int c0 = cs + half * 8;
        float accv[8];
        #pragma unroll
        for (int j = 0; j < 8; j++) accv[j] = 0.f;
        #pragma unroll
        for (int pp = 0; pp < 4; pp++) {
            short8v ov = *(const short8v*)&pO[(size_t)(Lb | (pp << 4)) * 4096 + r * 64 + c0];
            #pragma unroll
            for (int j = 0; j < 8; j++) accv[j] += bf2f(ov[j]) * a[pp];
        }
        short8v res;
        #pragma unroll
        for (int j = 0; j < 8; j++) res[j] = f2bf(accv[j] * inv);
        *(short8v*)&aout[(size_t)(b * 2048 + q0 + r) * 512 + h * 64 + c0] = res;
    }
}

// ---------------------------------------------------------------------------
extern "C" void kernel_launch(void* const* d_in, const int* in_sizes, int n_in,
                              void* d_out, int out_size, void* d_ws, size_t ws_size,
                              hipStream_t stream) {
    const float* x      = (const float*)d_in[0];
    const float* conv_w = (const float*)d_in[1];
    const float* conv_b = (const float*)d_in[2];
    const float* g1     = (const float*)d_in[3];
    const float* b1     = (const float*)d_in[4];
    const float* qkv_w  = (const float*)d_in[5];
    const float* qkv_b  = (const float*)d_in[6];
    const float* proj_w = (const float*)d_in[7];
    const float* proj_b = (const float*)d_in[8];
    const float* g2     = (const float*)d_in[9];
    const float* b2     = (const float*)d_in[10];
    const float* ffn_w1 = (const float*)d_in[11];
    const float* ffn_b1 = (const float*)d_in[12];
    const float* ffn_w2 = (const float*)d_in[13];
    const float* ffn_b2 = (const float*)d_in[14];
    const float* g3     = (const float*)d_in[15];
    const float* b3     = (const float*)d_in[16];
    float* out = (float*)d_out;

    char* p = (char*)d_ws;
    short* cwT   = (short*)p;  p += 786432 * 2;
    short* qkvT  = (short*)p;  p += 786432 * 2;
    short* projT = (short*)p;  p += 262144 * 2;
    short* f1T   = (short*)p;  p += 524288 * 2;
    short* f2T   = (short*)p;  p += 524288 * 2;
    short* xpad  = (short*)p;  p += 2099200 * 2;
    short* yb    = (short*)p;  p += 2097152 * 2;   // bf16 pre-LN activations
    short* x1b   = (short*)p;  p += 2097152 * 2;   // LN1 out (qkv A + proj res)
    short* qkvb  = (short*)p;  p += 6291456 * 2;
    short* vTb   = (short*)p;  p += 2097152 * 2;
    short* pO    = (short*)p;  p += 8388608 * 2;   // 2048 x 64 x 64 bf16 partial O
    float* pML   = (float*)p;  p += 262144 * 4;    // 2048 x (m[64] | l[64])
    // aliases of dead buffers:
    short* x2b     = x1b;   // x1b dead after proj epilogue (its last reader)
    short* hb      = qkvb;  // qkvb dead after attention
    short* attnout = xpad;  // xpad dead after conv GEMM

    prep_all<<<4097, 256, 0, stream>>>(conv_w, x, qkv_w, proj_w, ffn_w1, ffn_w2,
                                       cwT, xpad, qkvT, projT, f1T, f2T);
    gemm_mfma<M_CONV, 64, 32, 128><<<dim3(64, 16), 128, 0, stream>>>(
        xpad, cwT, conv_b, x, yb, nullptr, 1536);
    ln_row<<<512, 512, 0, stream>>>(yb, g1, b1, nullptr, x1b);
    gemm_mfma<M_QKV, 128, 64, 64><<<dim3(32, 24), 256, 0, stream>>>(
        x1b, qkvT, qkv_b, nullptr, qkvb, vTb, 512);
    attn_part<<<2048, 256, 0, stream>>>(qkvb, vTb, pO, pML);
    attn_merge<<<512, 256, 0, stream>>>(pO, pML, attnout);
    gemm_mfma<M_PROJ, 64, 32, 128><<<dim3(64, 16), 128, 0, stream>>>(
        attnout, projT, proj_b, x1b, yb, nullptr, 512);
    ln_row<<<512, 512, 0, stream>>>(yb, g2, b2, nullptr, x2b);
    gemm_mfma<M_FFN1, 128, 64, 64><<<dim3(32, 16), 256, 0, stream>>>(
        x2b, f1T, ffn_b1, nullptr, hb, nullptr, 512);
    gemm_mfma<M_FFN2, 64, 32, 128><<<dim3(64, 16), 128, 0, stream>>>(
        hb, f2T, ffn_b2, x2b, yb, nullptr, 1024);
    ln_row<<<512, 512, 0, stream>>>(yb, g3, b3, out, nullptr);
}